// Round 15
// baseline (58.860 us; speedup 1.0000x reference)
//
#include <hip/hip_runtime.h>

#define B 16
#define CIN 4
#define COUT 8
#define KW 5
#define S 2048
#define BS (B * S)

// DIAGNOSTIC: repeat conv body CREP times (idempotent: same values stored
// each rep; asm pointer clobber defeats LICM/CSE so loads+math+stores all
// re-execute). conv_marginal = (dur - 19.5)/(CREP-1). Attn is byte-identical
// to R14.
#define CREP 32

typedef _Float16 f16;
typedef _Float16 f16x4 __attribute__((ext_vector_type(4)));
typedef _Float16 f16x8 __attribute__((ext_vector_type(8)));
typedef __fp16 fp16x2 __attribute__((ext_vector_type(2)));
typedef float f32x16 __attribute__((ext_vector_type(16)));

// V^T fragment ordering within a 32-kv tile (A-operand of PV MFMA):
__device__ __forceinline__ int vfrag_off(int k) {
    return (((k >> 2) & 1) << 4) | (((k >> 4) & 1) << 3) | (k & 3) | (((k >> 3) & 1) << 2);
}

// ---------------------------------------------------------------------------
// Kernel 1: three causal (reflect-padded) convs, body repeated CREP times.
// part 0: qe = conv(q, wq) * QSCALE -> [b][s][8] f16   (exp2-domain scale)
// part 1: ke = conv(v, wk)          -> [b][s][8] f16   (swapped wiring!)
// part 2: ve = conv(k, wv)          -> vt2 [b][tile][n][frag-order] f16,
//          row n=8 = 1.0 (ones row -> softmax denominator via PV MFMA).
// ---------------------------------------------------------------------------
__global__ __launch_bounds__(256) void conv_embed_kernel(
    const float* __restrict__ q, const float* __restrict__ k,
    const float* __restrict__ v, const float* __restrict__ wq,
    const float* __restrict__ wk, const float* __restrict__ wv,
    f16* __restrict__ qe, f16* __restrict__ ke, f16* __restrict__ vt2)
{
    __shared__ float wsm[80];

    int tid  = threadIdx.x;
    int blk  = blockIdx.x & 127;
    int grp  = blockIdx.x >> 7;    // 0..5
    int part = grp >> 1;           // 0,1,2
    int oh   = grp & 1;            // oc half

    const float* in; const float* wsrc;
    if (part == 0)      { in = q; wsrc = wq; }
    else if (part == 1) { in = v; wsrc = wk; }   // ke = conv(v, wk)
    else                { in = k; wsrc = wv; }   // ve = conv(k, wv)

    if (tid < 80) wsm[tid] = wsrc[oh * 80 + tid];
    __syncthreads();

    int gid = blk * 256 + tid;     // b*S + s
    int s = gid & (S - 1);
    int b = gid >> 11;

    const float QSCALE = 0.35355339059327373f * 1.4426950408889634f; // (1/sqrt8)*log2e

#pragma unroll 1
    for (int rep = 0; rep < CREP; ++rep) {
        const float* ip0 = in;
        f16* oq = qe; f16* ok = ke; f16* ov = vt2;
        // Opaque barrier: forces full re-execution each rep (rule #17).
        asm volatile("" : "+v"(ip0), "+v"(oq), "+v"(ok), "+v"(ov));

        float x[CIN][KW];
#pragma unroll
        for (int c = 0; c < CIN; ++c) {
            const float* ip = ip0 + ((size_t)(b * CIN + c) << 11);
#pragma unroll
            for (int i = 0; i < KW; ++i) {
                int idx = s + i - 4;
                idx = idx < 0 ? -idx : idx;   // reflect pad
                x[c][i] = ip[idx];
            }
        }

        float o[4];
#pragma unroll
        for (int oo = 0; oo < 4; ++oo) {
            float a = 0.f;
#pragma unroll
            for (int c = 0; c < CIN; ++c)
#pragma unroll
                for (int i = 0; i < KW; ++i)
                    a += x[c][i] * wsm[oo * 20 + c * 5 + i];
            o[oo] = a;
        }

        if (part == 2) {
            int t   = s >> 5;
            int off = vfrag_off(s & 31);
            size_t base = (size_t)(b * 64 + t) * 9;
#pragma unroll
            for (int oo = 0; oo < 4; ++oo)
                ov[((base + oh * 4 + oo) << 5) + off] = (f16)o[oo];
            if (oh == 0)                                   // ones row (n = 8)
                ov[((base + 8) << 5) + off] = (f16)1.0f;
        } else {
            float sc = (part == 0) ? QSCALE : 1.0f;
            f16x4 r;
#pragma unroll
            for (int oo = 0; oo < 4; ++oo) r[oo] = (f16)(o[oo] * sc);
            f16* dst = ((part == 0) ? oq : ok) + ((size_t)gid << 3) + oh * 4;
            *(f16x4*)dst = r;
        }
    }
}

// ---------------------------------------------------------------------------
// Kernel 2: flash attention (byte-identical to R14).
// ---------------------------------------------------------------------------
#define QT 32
#define NWAVE 8
#define KVC (S / NWAVE)   // 256 kv per wave

#if __has_builtin(__builtin_amdgcn_mfma_f32_32x32x8f16)
#define HAVE_K8 1
#else
#define HAVE_K8 0
#endif

__global__ __launch_bounds__(512, 4) void attn_mfma_kernel(
    const f16* __restrict__ qe, const f16* __restrict__ ke,
    const f16* __restrict__ vt2, const float* __restrict__ w_out,
    const float* __restrict__ b_out, float* __restrict__ out)
{
    __shared__ float red[NWAVE][9][QT];

    int tid  = threadIdx.x;
    int w    = tid >> 6;
    int lane = tid & 63;
    int hi   = lane >> 5;
    int ln   = lane & 31;

    int b  = blockIdx.x >> 6;      // 64 q-tiles per batch
    int q0 = (blockIdx.x & 63) * QT;

    // Q fragment (B operand): elems 0..3 = Q[q0+ln][4*hi..4*hi+3]
    f16x4 qb4 = *(const f16x4*)(qe + ((size_t)(b * S + q0 + ln) << 3) + hi * 4);
#if !HAVE_K8
    f16x8 qb8 = {qb4[0], qb4[1], qb4[2], qb4[3], (f16)0, (f16)0, (f16)0, (f16)0};
#endif

    const f32x16 zero16 = {};
    f32x16 oacc = {};              // C[n][q]; row n=8 accumulates l

    int vrow = ln < 9 ? ln : 8;    // row-clamp: lanes 9..31 -> row 8 (don't-care)
    const f16* kptr = ke + ((size_t)(b * S + w * KVC + ln) << 3) + hi * 4;
    const f16* vptr = vt2 + (((size_t)(b * 64 + w * (KVC / 32)) * 9 + vrow) << 5) + hi * 16;

#pragma unroll
    for (int it = 0; it < KVC / 32; ++it) {
        // ---- QK^T (C-in = persistent zero) ----
        f16x4 kh = *(const f16x4*)kptr;
        kptr += 32 * 8;
#if HAVE_K8
        f32x16 sc = __builtin_amdgcn_mfma_f32_32x32x8f16(kh, qb4, zero16, 0, 0, 0);
#else
        f16x8 ka = {kh[0], kh[1], kh[2], kh[3], (f16)0, (f16)0, (f16)0, (f16)0};
        f32x16 sc = __builtin_amdgcn_mfma_f32_32x32x16_f16(ka, qb8, zero16, 0, 0, 0);
#endif

        // ---- exp2 fused into f16 pack (owned C-rows == needed B-frag k) ----
        union { f16x8 v; fp16x2 h[4]; } p1, p2;
#pragma unroll
        for (int i = 0; i < 4; ++i) {
            p1.h[i] = __builtin_amdgcn_cvt_pkrtz(__builtin_amdgcn_exp2f(sc[2 * i]),
                                                 __builtin_amdgcn_exp2f(sc[2 * i + 1]));
            p2.h[i] = __builtin_amdgcn_cvt_pkrtz(__builtin_amdgcn_exp2f(sc[8 + 2 * i]),
                                                 __builtin_amdgcn_exp2f(sc[8 + 2 * i + 1]));
        }

        // ---- V^T A-fragments: unconditional row-clamped loads ----
        f16x8 va1 = *(const f16x8*)(vptr);
        f16x8 va2 = *(const f16x8*)(vptr + 8);
        vptr += 9 * 32;

        oacc = __builtin_amdgcn_mfma_f32_32x32x16_f16(va1, p1.v, oacc, 0, 0, 0);
        oacc = __builtin_amdgcn_mfma_f32_32x32x16_f16(va2, p2.v, oacc, 0, 0, 0);
    }

    // ---- epilogue: dump useful C rows (n<9) to LDS ----
#pragma unroll
    for (int r = 0; r < 16; ++r) {
        int n = (r & 3) + 8 * (r >> 2) + 4 * hi;
        if (n < 9) red[w][n][ln] = oacc[r];
    }
    __syncthreads();

    // Reduce the 8 kv-chunk waves: 9 rows x 32 q = 288 items (512 threads).
    if (tid < 9 * QT) {
        int n = tid >> 5, qq = tid & 31;
        float a = red[0][n][qq];
#pragma unroll
        for (int ww = 1; ww < NWAVE; ++ww) a += red[ww][n][qq];
        red[0][n][qq] = a;
    }
    __syncthreads();

    if (tid < 256) {
        int cp = tid >> 5, qq = tid & 31;   // 8 channels x 32 q
        float inv = 1.0f / red[0][8][qq];
        float y = b_out[cp];
#pragma unroll
        for (int c = 0; c < 8; ++c) y += w_out[cp * 8 + c] * red[0][c][qq] * inv;
        out[(((size_t)(b * COUT + cp)) << 11) + q0 + qq] = y;
    }
}

// ---------------------------------------------------------------------------
extern "C" void kernel_launch(void* const* d_in, const int* in_sizes, int n_in,
                              void* d_out, int out_size, void* d_ws, size_t ws_size,
                              hipStream_t stream)
{
    const float* q     = (const float*)d_in[0];
    const float* k     = (const float*)d_in[1];
    const float* v     = (const float*)d_in[2];
    const float* wq    = (const float*)d_in[3];
    const float* wk    = (const float*)d_in[4];
    const float* wv    = (const float*)d_in[5];
    const float* w_out = (const float*)d_in[6];
    const float* b_out = (const float*)d_in[7];
    float* out = (float*)d_out;

    f16* qe  = (f16*)d_ws;                       // [B][S][8]
    f16* ke  = qe + (size_t)BS * COUT;           // [B][S][8]
    f16* vt2 = ke + (size_t)BS * COUT;           // [B][64][9][32] frag-ordered

    conv_embed_kernel<<<768, 256, 0, stream>>>(q, k, v, wq, wk, wv, qe, ke, vt2);
    attn_mfma_kernel<<<B * (S / QT), 512, 0, stream>>>(qe, ke, vt2, w_out, b_out, out);
}

// Round 16
// 19.855 us; speedup vs baseline: 2.9645x; 2.9645x over previous
//
#include <hip/hip_runtime.h>

#define B 16
#define CIN 4
#define COUT 8
#define KW 5
#define S 2048
#define BS (B * S)

typedef _Float16 f16;
typedef _Float16 f16x4 __attribute__((ext_vector_type(4)));
typedef _Float16 f16x8 __attribute__((ext_vector_type(8)));
typedef __fp16 fp16x2 __attribute__((ext_vector_type(2)));
typedef float f32x16 __attribute__((ext_vector_type(16)));

// V^T fragment ordering within a 32-kv tile (A-operand of PV MFMA):
__device__ __forceinline__ int vfrag_off(int k) {
    return (((k >> 2) & 1) << 4) | (((k >> 4) & 1) << 3) | (k & 3) | (((k >> 3) & 1) << 2);
}

// ---------------------------------------------------------------------------
// Kernel 1: three causal (reflect-padded) convs (R14 verbatim).
// part 0: qe = conv(q, wq) * QSCALE -> [b][s][8] f16   (exp2-domain scale)
// part 1: ke = conv(v, wk)          -> [b][s][8] f16   (swapped wiring!)
// part 2: ve = conv(k, wv)          -> vt2 [b][tile][n][frag-order] f16,
//          row n=8 = 1.0 (ones row -> softmax denominator via PV MFMA).
// ---------------------------------------------------------------------------
__global__ __launch_bounds__(256) void conv_embed_kernel(
    const float* __restrict__ q, const float* __restrict__ k,
    const float* __restrict__ v, const float* __restrict__ wq,
    const float* __restrict__ wk, const float* __restrict__ wv,
    f16* __restrict__ qe, f16* __restrict__ ke, f16* __restrict__ vt2)
{
    __shared__ float wsm[80];

    int tid  = threadIdx.x;
    int blk  = blockIdx.x & 127;
    int grp  = blockIdx.x >> 7;    // 0..5
    int part = grp >> 1;           // 0,1,2
    int oh   = grp & 1;            // oc half

    const float* in; const float* wsrc;
    if (part == 0)      { in = q; wsrc = wq; }
    else if (part == 1) { in = v; wsrc = wk; }   // ke = conv(v, wk)
    else                { in = k; wsrc = wv; }   // ve = conv(k, wv)

    if (tid < 80) wsm[tid] = wsrc[oh * 80 + tid];
    __syncthreads();

    int gid = blk * 256 + tid;     // b*S + s
    int s = gid & (S - 1);
    int b = gid >> 11;

    float x[CIN][KW];
#pragma unroll
    for (int c = 0; c < CIN; ++c) {
        const float* ip = in + ((size_t)(b * CIN + c) << 11);
#pragma unroll
        for (int i = 0; i < KW; ++i) {
            int idx = s + i - 4;
            idx = idx < 0 ? -idx : idx;   // reflect pad
            x[c][i] = ip[idx];
        }
    }

    float o[4];
#pragma unroll
    for (int oo = 0; oo < 4; ++oo) {
        float a = 0.f;
#pragma unroll
        for (int c = 0; c < CIN; ++c)
#pragma unroll
            for (int i = 0; i < KW; ++i)
                a += x[c][i] * wsm[oo * 20 + c * 5 + i];
        o[oo] = a;
    }

    const float QSCALE = 0.35355339059327373f * 1.4426950408889634f; // (1/sqrt8)*log2e

    if (part == 2) {
        int t   = s >> 5;
        int off = vfrag_off(s & 31);
        size_t base = (size_t)(b * 64 + t) * 9;
#pragma unroll
        for (int oo = 0; oo < 4; ++oo)
            vt2[((base + oh * 4 + oo) << 5) + off] = (f16)o[oo];
        if (oh == 0)                                   // ones row (n = 8)
            vt2[((base + 8) << 5) + off] = (f16)1.0f;
    } else {
        float sc = (part == 0) ? QSCALE : 1.0f;
        f16x4 r;
#pragma unroll
        for (int oo = 0; oo < 4; ++oo) r[oo] = (f16)(o[oo] * sc);
        f16* dst = ((part == 0) ? qe : ke) + ((size_t)gid << 3) + oh * 4;
        *(f16x4*)dst = r;
    }
}

// ---------------------------------------------------------------------------
// Kernel 2: flash attention. R16 change: manual MLP for the cold pass.
// All 8 K fragments hoisted (independent loads, one latency instead of 8);
// V double-buffered with depth-2 prefetch issued before the exp chain.
// Loop fully unrolled -> all buffer indices static (rule #20). Clamped
// prefetch index is compile-time; tail prefetches re-read tile 7 (warm).
//
// SPLIT-K fragment layout:
//   32x32x8  A/B: lane l elem j <-> k = (l>>5)*4 + j
//   C/D: col = lane&31, row = (r&3) + 8*(r>>2) + 4*(lane>>5)
// QK^T swapped: C[kv][q] = mfma(A=K, B=Q^T); p = exp2(C) feeds PV's B
// fragment DIRECTLY. PV: C[n][q] += mfma(A=V^T, B=P) x2; row n==8 (ones row
// in vt2) accumulates the softmax denominator l. Lanes 9..31 use row-clamped
// V pointers (their C rows are never read).
// ---------------------------------------------------------------------------
#define QT 32
#define NWAVE 8
#define KVC (S / NWAVE)   // 256 kv per wave; KVC/32 = 8 tiles

#if __has_builtin(__builtin_amdgcn_mfma_f32_32x32x8f16)
#define HAVE_K8 1
#else
#define HAVE_K8 0
#endif

__global__ __launch_bounds__(512, 4) void attn_mfma_kernel(
    const f16* __restrict__ qe, const f16* __restrict__ ke,
    const f16* __restrict__ vt2, const float* __restrict__ w_out,
    const float* __restrict__ b_out, float* __restrict__ out)
{
    __shared__ float red[NWAVE][9][QT];

    int tid  = threadIdx.x;
    int w    = tid >> 6;
    int lane = tid & 63;
    int hi   = lane >> 5;
    int ln   = lane & 31;

    int b  = blockIdx.x >> 6;      // 64 q-tiles per batch
    int q0 = (blockIdx.x & 63) * QT;

    // Q fragment (B operand): elems 0..3 = Q[q0+ln][4*hi..4*hi+3]
    f16x4 qb4 = *(const f16x4*)(qe + ((size_t)(b * S + q0 + ln) << 3) + hi * 4);
#if !HAVE_K8
    f16x8 qb8 = {qb4[0], qb4[1], qb4[2], qb4[3], (f16)0, (f16)0, (f16)0, (f16)0};
#endif

    const f32x16 zero16 = {};
    f32x16 oacc = {};              // C[n][q]; row n=8 accumulates l

    int vrow = ln < 9 ? ln : 8;    // row-clamp: lanes 9..31 -> row 8 (don't-care)
    const f16* kbase = ke + ((size_t)(b * S + w * KVC + ln) << 3) + hi * 4;
    const f16* vbase = vt2 + (((size_t)(b * 64 + w * 8) * 9 + vrow) << 5) + hi * 16;

    // ---- hoist ALL K fragments: 8 independent loads, one latency ----
    f16x4 kf[8];
#pragma unroll
    for (int it = 0; it < 8; ++it)
        kf[it] = *(const f16x4*)(kbase + it * (32 * 8));

    // ---- V depth-2 rotating prefetch ----
    f16x8 va1[2], va2[2];
    va1[0] = *(const f16x8*)(vbase);
    va2[0] = *(const f16x8*)(vbase + 8);
    va1[1] = *(const f16x8*)(vbase + 288);
    va2[1] = *(const f16x8*)(vbase + 288 + 8);

#pragma unroll
    for (int it = 0; it < 8; ++it) {
        // current V operands (rename; buffers get overwritten by prefetch)
        f16x8 v1 = va1[it & 1];
        f16x8 v2 = va2[it & 1];

        // prefetch tile it+2 (clamped; compile-time constant after unroll)
        int jn = (it + 2 <= 7) ? it + 2 : 7;
        va1[it & 1] = *(const f16x8*)(vbase + jn * 288);
        va2[it & 1] = *(const f16x8*)(vbase + jn * 288 + 8);

        // ---- QK^T (C-in = persistent zero) ----
#if HAVE_K8
        f32x16 sc = __builtin_amdgcn_mfma_f32_32x32x8f16(kf[it], qb4, zero16, 0, 0, 0);
#else
        f16x8 ka = {kf[it][0], kf[it][1], kf[it][2], kf[it][3],
                    (f16)0, (f16)0, (f16)0, (f16)0};
        f32x16 sc = __builtin_amdgcn_mfma_f32_32x32x16_f16(ka, qb8, zero16, 0, 0, 0);
#endif

        // ---- exp2 fused into f16 pack (owned C-rows == needed B-frag k) ----
        union { f16x8 v; fp16x2 h[4]; } p1, p2;
#pragma unroll
        for (int i = 0; i < 4; ++i) {
            p1.h[i] = __builtin_amdgcn_cvt_pkrtz(__builtin_amdgcn_exp2f(sc[2 * i]),
                                                 __builtin_amdgcn_exp2f(sc[2 * i + 1]));
            p2.h[i] = __builtin_amdgcn_cvt_pkrtz(__builtin_amdgcn_exp2f(sc[8 + 2 * i]),
                                                 __builtin_amdgcn_exp2f(sc[8 + 2 * i + 1]));
        }

        // ---- PV ----
        oacc = __builtin_amdgcn_mfma_f32_32x32x16_f16(v1, p1.v, oacc, 0, 0, 0);
        oacc = __builtin_amdgcn_mfma_f32_32x32x16_f16(v2, p2.v, oacc, 0, 0, 0);
    }

    // ---- epilogue: dump useful C rows (n<9) to LDS ----
#pragma unroll
    for (int r = 0; r < 16; ++r) {
        int n = (r & 3) + 8 * (r >> 2) + 4 * hi;
        if (n < 9) red[w][n][ln] = oacc[r];
    }
    __syncthreads();

    // Reduce the 8 kv-chunk waves: 9 rows x 32 q = 288 items (512 threads).
    if (tid < 9 * QT) {
        int n = tid >> 5, qq = tid & 31;
        float a = red[0][n][qq];
#pragma unroll
        for (int ww = 1; ww < NWAVE; ++ww) a += red[ww][n][qq];
        red[0][n][qq] = a;
    }
    __syncthreads();

    if (tid < 256) {
        int cp = tid >> 5, qq = tid & 31;   // 8 channels x 32 q
        float inv = 1.0f / red[0][8][qq];
        float y = b_out[cp];
#pragma unroll
        for (int c = 0; c < 8; ++c) y += w_out[cp * 8 + c] * red[0][c][qq] * inv;
        out[(((size_t)(b * COUT + cp)) << 11) + q0 + qq] = y;
    }
}

// ---------------------------------------------------------------------------
extern "C" void kernel_launch(void* const* d_in, const int* in_sizes, int n_in,
                              void* d_out, int out_size, void* d_ws, size_t ws_size,
                              hipStream_t stream)
{
    const float* q     = (const float*)d_in[0];
    const float* k     = (const float*)d_in[1];
    const float* v     = (const float*)d_in[2];
    const float* wq    = (const float*)d_in[3];
    const float* wk    = (const float*)d_in[4];
    const float* wv    = (const float*)d_in[5];
    const float* w_out = (const float*)d_in[6];
    const float* b_out = (const float*)d_in[7];
    float* out = (float*)d_out;

    f16* qe  = (f16*)d_ws;                       // [B][S][8]
    f16* ke  = qe + (size_t)BS * COUT;           // [B][S][8]
    f16* vt2 = ke + (size_t)BS * COUT;           // [B][64][9][32] frag-ordered

    conv_embed_kernel<<<768, 256, 0, stream>>>(q, k, v, wq, wk, wv, qe, ke, vt2);
    attn_mfma_kernel<<<B * (S / QT), 512, 0, stream>>>(qe, ke, vt2, w_out, b_out, out);
}

// Round 17
// 18.795 us; speedup vs baseline: 3.1318x; 1.0564x over previous
//
#include <hip/hip_runtime.h>

#define B 16
#define CIN 4
#define COUT 8
#define KW 5
#define S 2048
#define BS (B * S)

typedef _Float16 f16;
typedef _Float16 f16x4 __attribute__((ext_vector_type(4)));
typedef _Float16 f16x8 __attribute__((ext_vector_type(8)));
typedef __fp16 fp16x2 __attribute__((ext_vector_type(2)));
typedef float f32x16 __attribute__((ext_vector_type(16)));

// V^T fragment ordering within a 32-kv tile (A-operand of PV MFMA):
__device__ __forceinline__ int vfrag_off(int k) {
    return (((k >> 2) & 1) << 4) | (((k >> 4) & 1) << 3) | (k & 3) | (((k >> 3) & 1) << 2);
}

// ---------------------------------------------------------------------------
// Kernel 1: three causal (reflect-padded) convs. R17: XCD co-location —
// batch b's position-blocks all run on XCD b&7 (blockIdx%8 -> XCD round-robin
// assumption), so conv's written-back lines stay clean-resident in the L2
// that attn's readers (same swizzle) run on.
// part 0: qe = conv(q, wq) * QSCALE -> [b][s][8] f16   (exp2-domain scale)
// part 1: ke = conv(v, wk)          -> [b][s][8] f16   (swapped wiring!)
// part 2: ve = conv(k, wv)          -> vt2 [b][tile][n][frag-order] f16,
//          row n=8 = 1.0 (ones row -> softmax denominator via PV MFMA).
// ---------------------------------------------------------------------------
__global__ __launch_bounds__(256) void conv_embed_kernel(
    const float* __restrict__ q, const float* __restrict__ k,
    const float* __restrict__ v, const float* __restrict__ wq,
    const float* __restrict__ wk, const float* __restrict__ wv,
    f16* __restrict__ qe, f16* __restrict__ ke, f16* __restrict__ vt2)
{
    __shared__ float wsm[80];

    int tid  = threadIdx.x;
    // XCD co-location swizzle (bijective over 768 = 8 xcd x 96 slots):
    int bid  = blockIdx.x;
    int xcd  = bid & 7;
    int slot = bid >> 3;           // 0..95
    int grp  = slot >> 4;          // 0..5
    int r    = slot & 15;
    int b    = xcd + ((r >> 3) << 3);   // batches {xcd, xcd+8}
    int chunk= r & 7;              // position chunk within batch
    int part = grp >> 1;           // 0,1,2
    int oh   = grp & 1;            // oc half

    const float* in; const float* wsrc;
    if (part == 0)      { in = q; wsrc = wq; }
    else if (part == 1) { in = v; wsrc = wk; }   // ke = conv(v, wk)
    else                { in = k; wsrc = wv; }   // ve = conv(k, wv)

    if (tid < 80) wsm[tid] = wsrc[oh * 80 + tid];
    __syncthreads();

    int s = chunk * 256 + tid;
    int gid = b * S + s;

    float x[CIN][KW];
#pragma unroll
    for (int c = 0; c < CIN; ++c) {
        const float* ip = in + ((size_t)(b * CIN + c) << 11);
#pragma unroll
        for (int i = 0; i < KW; ++i) {
            int idx = s + i - 4;
            idx = idx < 0 ? -idx : idx;   // reflect pad
            x[c][i] = ip[idx];
        }
    }

    float o[4];
#pragma unroll
    for (int oo = 0; oo < 4; ++oo) {
        float a = 0.f;
#pragma unroll
        for (int c = 0; c < CIN; ++c)
#pragma unroll
            for (int i = 0; i < KW; ++i)
                a += x[c][i] * wsm[oo * 20 + c * 5 + i];
        o[oo] = a;
    }

    const float QSCALE = 0.35355339059327373f * 1.4426950408889634f; // (1/sqrt8)*log2e

    if (part == 2) {
        int t   = s >> 5;
        int off = vfrag_off(s & 31);
        size_t base = (size_t)(b * 64 + t) * 9;
#pragma unroll
        for (int oo = 0; oo < 4; ++oo)
            vt2[((base + oh * 4 + oo) << 5) + off] = (f16)o[oo];
        if (oh == 0)                                   // ones row (n = 8)
            vt2[((base + 8) << 5) + off] = (f16)1.0f;
    } else {
        float sc = (part == 0) ? QSCALE : 1.0f;
        f16x4 r4;
#pragma unroll
        for (int oo = 0; oo < 4; ++oo) r4[oo] = (f16)(o[oo] * sc);
        f16* dst = ((part == 0) ? qe : ke) + ((size_t)gid << 3) + oh * 4;
        *(f16x4*)dst = r4;
    }
}

// ---------------------------------------------------------------------------
// Kernel 2: flash attention (R14 inner loop verbatim). R17: XCD co-location —
// all 64 q-tile blocks of batch b run on XCD b&7, sharing that XCD's L2 for
// the batch's K/V first-touches (and hitting conv's clean-resident lines).
//
// SPLIT-K fragment layout:
//   32x32x8  A/B: lane l elem j <-> k = (l>>5)*4 + j
//   C/D: col = lane&31, row = (r&3) + 8*(r>>2) + 4*(lane>>5)
// QK^T swapped: C[kv][q] = mfma(A=K, B=Q^T); p = exp2(C) feeds PV's B
// fragment DIRECTLY. PV: C[n][q] += mfma(A=V^T, B=P) x2; row n==8 (ones row
// in vt2) accumulates denominator l. Lanes 9..31: row-clamped V pointer.
// ---------------------------------------------------------------------------
#define QT 32
#define NWAVE 8
#define KVC (S / NWAVE)   // 256 kv per wave

#if __has_builtin(__builtin_amdgcn_mfma_f32_32x32x8f16)
#define HAVE_K8 1
#else
#define HAVE_K8 0
#endif

__global__ __launch_bounds__(512, 4) void attn_mfma_kernel(
    const f16* __restrict__ qe, const f16* __restrict__ ke,
    const f16* __restrict__ vt2, const float* __restrict__ w_out,
    const float* __restrict__ b_out, float* __restrict__ out)
{
    __shared__ float red[NWAVE][9][QT];

    int tid  = threadIdx.x;
    int w    = tid >> 6;
    int lane = tid & 63;
    int hi   = lane >> 5;
    int ln   = lane & 31;

    // XCD co-location swizzle (bijective over 1024 = 8 xcd x 128 slots):
    int bid  = blockIdx.x;
    int xcd  = bid & 7;
    int slot = bid >> 3;           // 0..127
    int b    = xcd + ((slot >> 6) << 3);   // batches {xcd, xcd+8}
    int q0   = (slot & 63) * QT;

    // Q fragment (B operand): elems 0..3 = Q[q0+ln][4*hi..4*hi+3]
    f16x4 qb4 = *(const f16x4*)(qe + ((size_t)(b * S + q0 + ln) << 3) + hi * 4);
#if !HAVE_K8
    f16x8 qb8 = {qb4[0], qb4[1], qb4[2], qb4[3], (f16)0, (f16)0, (f16)0, (f16)0};
#endif

    const f32x16 zero16 = {};
    f32x16 oacc = {};              // C[n][q]; row n=8 accumulates l

    int vrow = ln < 9 ? ln : 8;    // row-clamp: lanes 9..31 -> row 8 (don't-care)
    const f16* kptr = ke + ((size_t)(b * S + w * KVC + ln) << 3) + hi * 4;
    const f16* vptr = vt2 + (((size_t)(b * 64 + w * (KVC / 32)) * 9 + vrow) << 5) + hi * 16;

#pragma unroll
    for (int it = 0; it < KVC / 32; ++it) {
        // ---- QK^T (C-in = persistent zero) ----
        f16x4 kh = *(const f16x4*)kptr;
        kptr += 32 * 8;
#if HAVE_K8
        f32x16 sc = __builtin_amdgcn_mfma_f32_32x32x8f16(kh, qb4, zero16, 0, 0, 0);
#else
        f16x8 ka = {kh[0], kh[1], kh[2], kh[3], (f16)0, (f16)0, (f16)0, (f16)0};
        f32x16 sc = __builtin_amdgcn_mfma_f32_32x32x16_f16(ka, qb8, zero16, 0, 0, 0);
#endif

        // ---- exp2 fused into f16 pack (owned C-rows == needed B-frag k) ----
        union { f16x8 v; fp16x2 h[4]; } p1, p2;
#pragma unroll
        for (int i = 0; i < 4; ++i) {
            p1.h[i] = __builtin_amdgcn_cvt_pkrtz(__builtin_amdgcn_exp2f(sc[2 * i]),
                                                 __builtin_amdgcn_exp2f(sc[2 * i + 1]));
            p2.h[i] = __builtin_amdgcn_cvt_pkrtz(__builtin_amdgcn_exp2f(sc[8 + 2 * i]),
                                                 __builtin_amdgcn_exp2f(sc[8 + 2 * i + 1]));
        }

        // ---- V^T A-fragments: unconditional row-clamped loads ----
        f16x8 va1 = *(const f16x8*)(vptr);
        f16x8 va2 = *(const f16x8*)(vptr + 8);
        vptr += 9 * 32;

        oacc = __builtin_amdgcn_mfma_f32_32x32x16_f16(va1, p1.v, oacc, 0, 0, 0);
        oacc = __builtin_amdgcn_mfma_f32_32x32x16_f16(va2, p2.v, oacc, 0, 0, 0);
    }

    // ---- epilogue: dump useful C rows (n<9) to LDS ----
#pragma unroll
    for (int r = 0; r < 16; ++r) {
        int n = (r & 3) + 8 * (r >> 2) + 4 * hi;
        if (n < 9) red[w][n][ln] = oacc[r];
    }
    __syncthreads();

    // Reduce the 8 kv-chunk waves: 9 rows x 32 q = 288 items (512 threads).
    if (tid < 9 * QT) {
        int n = tid >> 5, qq = tid & 31;
        float a = red[0][n][qq];
#pragma unroll
        for (int ww = 1; ww < NWAVE; ++ww) a += red[ww][n][qq];
        red[0][n][qq] = a;
    }
    __syncthreads();

    if (tid < 256) {
        int cp = tid >> 5, qq = tid & 31;   // 8 channels x 32 q
        float inv = 1.0f / red[0][8][qq];
        float y = b_out[cp];
#pragma unroll
        for (int c = 0; c < 8; ++c) y += w_out[cp * 8 + c] * red[0][c][qq] * inv;
        out[(((size_t)(b * COUT + cp)) << 11) + q0 + qq] = y;
    }
}

// ---------------------------------------------------------------------------
extern "C" void kernel_launch(void* const* d_in, const int* in_sizes, int n_in,
                              void* d_out, int out_size, void* d_ws, size_t ws_size,
                              hipStream_t stream)
{
    const float* q     = (const float*)d_in[0];
    const float* k     = (const float*)d_in[1];
    const float* v     = (const float*)d_in[2];
    const float* wq    = (const float*)d_in[3];
    const float* wk    = (const float*)d_in[4];
    const float* wv    = (const float*)d_in[5];
    const float* w_out = (const float*)d_in[6];
    const float* b_out = (const float*)d_in[7];
    float* out = (float*)d_out;

    f16* qe  = (f16*)d_ws;                       // [B][S][8]
    f16* ke  = qe + (size_t)BS * COUT;           // [B][S][8]
    f16* vt2 = ke + (size_t)BS * COUT;           // [B][64][9][32] frag-ordered

    conv_embed_kernel<<<768, 256, 0, stream>>>(q, k, v, wq, wk, wv, qe, ke, vt2);
    attn_mfma_kernel<<<B * (S / QT), 512, 0, stream>>>(qe, ke, vt2, w_out, b_out, out);
}